// Round 13
// baseline (151.703 us; speedup 1.0000x reference)
//
#include <hip/hip_runtime.h>
#include <hip/hip_bf16.h>
#include <hip/hip_fp8.h>
#include <math.h>

typedef __attribute__((ext_vector_type(4))) int   int4v;
typedef __attribute__((ext_vector_type(8))) int   int8v;
typedef __attribute__((ext_vector_type(4))) float f32x4;

#define BM 128
#define BN 128
#define BK 128   // fp8: one 16x16x128 MFMA consumes the whole staged K-slab

union frag_u { int8v v; int4v h[2]; };

// ---------------------------------------------------------------------------
// prep: byte-identical to round 4.
// ---------------------------------------------------------------------------
__global__ __launch_bounds__(256) void prep_kernel(
    const float* __restrict__ X, const float* __restrict__ S,
    unsigned char* __restrict__ Xq, unsigned char* __restrict__ Sq,
    float* __restrict__ x2, float* __restrict__ s2,
    float* __restrict__ rowsum, int M, int R, int Dv)
{
    const int gid  = blockIdx.x * 256 + threadIdx.x;
    const int nthr = gridDim.x * 256;

    for (int i = gid; i < M; i += nthr) rowsum[i] = 0.f;

    const int lane = threadIdx.x & 63;
    const int wid  = gid >> 6;
    const int nw   = nthr >> 6;

    for (int row = wid; row < R; row += nw) {
        const float* rp;
        unsigned char* op;
        float* sq;
        if (row < M) { rp = X + (size_t)row * Dv;       op = Xq + (size_t)row * Dv;       sq = x2 + row; }
        else         { rp = S + (size_t)(row - M) * Dv; op = Sq + (size_t)(row - M) * Dv; sq = s2 + (row - M); }

        float acc = 0.f;
        for (int k = lane * 8; k < Dv; k += 64 * 8) {
            float4 v0 = *(const float4*)(rp + k);
            float4 v1 = *(const float4*)(rp + k + 4);
            acc += v0.x * v0.x + v0.y * v0.y + v0.z * v0.z + v0.w * v0.w;
            acc += v1.x * v1.x + v1.y * v1.y + v1.z * v1.z + v1.w * v1.w;
            int lo = __builtin_amdgcn_cvt_pk_fp8_f32(v0.x, v0.y, 0, false);
            lo     = __builtin_amdgcn_cvt_pk_fp8_f32(v0.z, v0.w, lo, true);
            int hi = __builtin_amdgcn_cvt_pk_fp8_f32(v1.x, v1.y, 0, false);
            hi     = __builtin_amdgcn_cvt_pk_fp8_f32(v1.z, v1.w, hi, true);
            union { int i2[2]; uint2 u; } pk;
            pk.i2[0] = lo; pk.i2[1] = hi;
            *(uint2*)(op + k) = pk.u;
        }
#pragma unroll
        for (int off = 1; off < 64; off <<= 1)
            acc += __shfl_xor(acc, off, 64);
        if (lane == 0) *sq = acc;
    }
}

// ---------------------------------------------------------------------------
// Fused fp8 GEMM + exp-reduce — SMALL-ACC / HIGH-OCCUPANCY variant.
// r11/r12 confirmed the 128-reg granule (occ 26->35% at <=128 total) but the
// 64x64-per-wave shape can't fit (needs ~136; spilled twice). This keeps the
// proven 128x128 tile / 2-barrier / XOR-involution machinery and changes the
// WAVE PARTITION: 512 threads, 8 waves x (64 rows x 32 cols).
//   acc 32 AGPR + ~60 VGPR ~ 92 total <= 128 (36-reg margin, not a squeeze)
//   -> 4 waves/SIMD budget -> 2 blocks/CU x 8 waves = 16 waves/CU (~50% occ).
// LDS reads/step rise to 96KB (x1.5/FLOP) — accepted: traffic cuts at fixed
// occ were null 3x (r3/r5-7); dur tracked occupancy in every experiment.
// Epilogue: wred LDS replaced by 4-step __shfl_xor l16-reduction (wred can't
// fit 8 waves; also deletes both epilogue barriers). Math identical to r9.
// Staging (512 thr): 2 rounds x 64 rows per operand; thread t: row
// rd*64+(t>>3), global chunk (t&7)^((t>>3)&7), HW dest = uniform+lane*16
// -> rd*8192 + t*16 linear ✓ (same involution as champion).
// Falsifier: WRITE_SIZE >> 4MB => spill => revert r9 & declare.
// ---------------------------------------------------------------------------
template<int DVC>
__global__ __launch_bounds__(512, 4) void kde_gemm_kernel(
    const unsigned char* __restrict__ Xq,   // [M][D] fp8 e4m3
    const unsigned char* __restrict__ Sq,   // [N][D] fp8 e4m3
    const float* __restrict__ x2,
    const float* __restrict__ s2,
    const float* __restrict__ scale_p,
    float* __restrict__ rowsum,
    int M, int N, int Dv)
{
    const int D = DVC ? DVC : Dv;

    __shared__ char smem[32768];   // A [0,16K), B [16K,32K)

    const int tid  = threadIdx.x;   // 0..511
    const int wave = tid >> 6;      // 0..7
    const int lane = tid & 63;
    const int quad = lane >> 4;
    const int l16  = lane & 15;

    const int m0 = blockIdx.x * BM;
    const int n0 = blockIdx.y * BN;
    const int wm = (wave & 1) * 64;   // 2 M-halves
    const int wn = (wave >> 1) * 32;  // 4 N-quarters

    const float sc = *scale_p;

    f32x4 acc[4][2] = {};             // 32 AGPR

    // staging: round rd covers rows rd*64..rd*64+63. Thread t: row-in-round
    // t>>3 (0..63), global 16B-chunk (t&7)^(row&7); HW writes uniform-base
    // + lane*16 -> LDS rd*8192 + t*16 (linear). Logical chunk c of row r
    // lands at physical slot c^(r&7) — the champion involution.
    const int srow0 = tid >> 3;                       // 0..63
    const int cg    = (tid & 7) ^ ((tid >> 3) & 7);
    const unsigned char* gA = Xq + (size_t)(m0 + srow0) * D + cg * 16;
    const ptrdiff_t bdiff = (Sq + (size_t)n0 * D) - (Xq + (size_t)m0 * D);
    const unsigned char* gB = gA + bdiff;             // SGPR-uniform diff

    // fragment LDS addressing ((row&7)==l16&7 since wm|8, wn|8, 16|8)
    const int e     = l16 & 7;
    const int offLo = ((2 * quad)     ^ e) * 16;
    const int offHi = ((2 * quad + 1) ^ e) * 16;
    const int aBase = (wm + l16) * 128;               // + mi*2048 imm
    const int bBase = 16384 + (wn + l16) * 128;       // + nj*2048 imm

#pragma unroll
    for (int k0 = 0; k0 < D; k0 += BK) {
        __syncthreads();  // prev iter's ds_reads done before overwrite
#pragma unroll
        for (int rd = 0; rd < 2; ++rd)                // A: 128 rows
            __builtin_amdgcn_global_load_lds(
                (const __attribute__((address_space(1))) void*)(gA + (size_t)rd * 64 * D + k0),
                (__attribute__((address_space(3))) void*)(smem + rd * 8192 + wave * 1024),
                16, 0, 0);
#pragma unroll
        for (int rd = 0; rd < 2; ++rd)                // B: 128 rows
            __builtin_amdgcn_global_load_lds(
                (const __attribute__((address_space(1))) void*)(gB + (size_t)rd * 64 * D + k0),
                (__attribute__((address_space(3))) void*)(smem + 16384 + rd * 8192 + wave * 1024),
                16, 0, 0);
        __syncthreads();  // staging drained

        frag_u a_frag[4];
#pragma unroll
        for (int mi = 0; mi < 4; ++mi) {
            a_frag[mi].h[0] = *(const int4v*)(smem + aBase + mi * 2048 + offLo);
            a_frag[mi].h[1] = *(const int4v*)(smem + aBase + mi * 2048 + offHi);
        }
#pragma unroll
        for (int nj = 0; nj < 2; ++nj) {
            frag_u b_frag;
            b_frag.h[0] = *(const int4v*)(smem + bBase + nj * 2048 + offLo);
            b_frag.h[1] = *(const int4v*)(smem + bBase + nj * 2048 + offHi);
#pragma unroll
            for (int mi = 0; mi < 4; ++mi)
                acc[mi][nj] = __builtin_amdgcn_mfma_scale_f32_16x16x128_f8f6f4(
                    a_frag[mi].v, b_frag.v, acc[mi][nj],
                    0, 0,                     // cbsz=fp8 e4m3, blgp=fp8 e4m3
                    0, 0x7F7F7F7F,            // A scales: unity E8M0
                    0, 0x7F7F7F7F);           // B scales: unity
        }
    }

    // ---- epilogue: r9 math; shuffle-reduce instead of wred LDS.
    // C layout per MFMA: col = l16 (-> n), row = quad*4 + reg (-> m).
    const float ke = -sc * 1.4426950408889634f;   // -scale * log2(e)  (< 0)
    const float c2 = -2.0f * ke;                  // +2 * scale * log2(e)

    float kes[2];
#pragma unroll
    for (int ni = 0; ni < 2; ++ni)
        kes[ni] = ke * s2[n0 + wn + ni * 16 + l16];

#pragma unroll
    for (int mi = 0; mi < 4; ++mi) {
        f32x4 kex;
#pragma unroll
        for (int r = 0; r < 4; ++r)
            kex[r] = ke * x2[m0 + wm + mi * 16 + quad * 4 + r];

        f32x4 vsum = {0.f, 0.f, 0.f, 0.f};
#pragma unroll
        for (int ni = 0; ni < 2; ++ni) {
            f32x4 arg = acc[mi][ni] * c2;
            arg = arg + kex;
#pragma unroll
            for (int r = 0; r < 4; ++r) {
                float a = fminf(arg[r] + kes[ni], 0.f);
                vsum[r] += __builtin_amdgcn_exp2f(a);
            }
        }
        // sum across the 16 l16 lanes of each quad (xor<16 keeps quad)
#pragma unroll
        for (int msk = 1; msk < 16; msk <<= 1)
#pragma unroll
            for (int r = 0; r < 4; ++r)
                vsum[r] += __shfl_xor(vsum[r], msk, 64);
        if (l16 == 0) {
#pragma unroll
            for (int r = 0; r < 4; ++r)
                atomicAdd(&rowsum[m0 + wm + mi * 16 + quad * 4 + r], vsum[r]);
        }
    }
}

// ---------------------------------------------------------------------------
__global__ void finalize_kernel(const float* __restrict__ rowsum,
                                const float* __restrict__ scale_p,
                                float* __restrict__ out, int M, int N, int Dv) {
    const int m = blockIdx.x * 256 + threadIdx.x;
    if (m < M) {
        const float sc = *scale_p;
        const float cst = -logf((float)N) + 0.5f * (float)Dv * logf(sc / 3.14159265358979f);
        out[m] = logf(rowsum[m]) + cst;
    }
}

// ---------------------------------------------------------------------------
extern "C" void kernel_launch(void* const* d_in, const int* in_sizes, int n_in,
                              void* d_out, int out_size, void* d_ws, size_t ws_size,
                              hipStream_t stream) {
    const float* X       = (const float*)d_in[0];
    const float* S       = (const float*)d_in[1];
    const float* scale_p = (const float*)d_in[2];
    float* out = (float*)d_out;

    const int M  = out_size;            // 8192
    const int Dv = in_sizes[0] / M;     // 512
    const int N  = in_sizes[1] / Dv;    // 8192

    char* ws = (char*)d_ws;
    unsigned char* Xq = (unsigned char*)ws;
    unsigned char* Sq = (unsigned char*)(ws + (size_t)M * Dv);
    float* x2     = (float*)(ws + (size_t)M * Dv + (size_t)N * Dv);
    float* s2     = x2 + M;
    float* rowsum = s2 + N;

    prep_kernel<<<2048, 256, 0, stream>>>(X, S, Xq, Sq, x2, s2, rowsum, M, M + N, Dv);

    dim3 grid(M / BM, N / BN);
    if (Dv == 512)
        kde_gemm_kernel<512><<<grid, 512, 0, stream>>>(Xq, Sq, x2, s2, scale_p, rowsum, M, N, Dv);
    else
        kde_gemm_kernel<0><<<grid, 512, 0, stream>>>(Xq, Sq, x2, s2, scale_p, rowsum, M, N, Dv);

    finalize_kernel<<<(M + 255) / 256, 256, 0, stream>>>(rowsum, scale_p, out, M, N, Dv);
}